// Round 6
// baseline (675.868 us; speedup 1.0000x reference)
//
#include <hip/hip_runtime.h>
#include <hip/hip_fp16.h>

#define N_NODES 100000
#define N_EDGES 3200000
#define E_TOT   (N_EDGES + N_NODES)   // 3.3M edges incl self-loops
#define IN_C 128
#define HID  16
#define OUTC 5
#define NEG_SLOPE 0.2f

#define NBKT 391          // buckets of 256 dst nodes: b = dst >> 8
#define CAP  9216         // per-bucket capacity (mean 8448, +8.3 sigma)
#define P1_TILE 8192
#define P1_GRID ((E_TOT + P1_TILE - 1) / P1_TILE)   // 403

__device__ __forceinline__ float pk_half2(float a, float b) {
    __half2 h = __halves2half2(__float2half(a), __float2half(b));
    return *(float*)&h;
}
__device__ __forceinline__ float2 unpk_half2(float v) {
    return __half22float2(*(__half2*)&v);
}

// ==================== phase 0: zero bucket totals ====================
__global__ void zero_gcnt_k(int* __restrict__ gcnt) {
    int i = blockIdx.x * blockDim.x + threadIdx.x;
    if (i < NBKT) gcnt[i] = 0;
}

// ==================== phase 1: partition edges by dst>>8 ====================
// packed entry: (src << 8) | (dst & 255)   (src < 2^17 -> fits 25 bits)
__global__ __launch_bounds__(256) void part_k(const int* __restrict__ ei,
                                              int* __restrict__ gcnt,
                                              unsigned* __restrict__ pairs) {
    __shared__ unsigned vbuf[P1_TILE];        // 32 KB
    __shared__ unsigned short bbuf[P1_TILE];  // 16 KB
    __shared__ int hist[NBKT];
    __shared__ int cur[NBKT];
    int t = threadIdx.x;
    for (int i = t; i < NBKT; i += 256) hist[i] = 0;
    __syncthreads();
    int base = blockIdx.x * P1_TILE;
    int lim = E_TOT - base; if (lim > P1_TILE) lim = P1_TILE;
    for (int i = t; i < lim; i += 256) {
        int e = base + i;
        int s, d;
        if (e < N_EDGES) { s = ei[e]; d = ei[N_EDGES + e]; }
        else             { s = e - N_EDGES; d = s; }
        int b = d >> 8;
        vbuf[i] = ((unsigned)s << 8) | (unsigned)(d & 255);
        bbuf[i] = (unsigned short)b;
        atomicAdd(&hist[b], 1);
    }
    __syncthreads();
    for (int i = t; i < NBKT; i += 256) {
        int h = hist[i];
        cur[i] = h ? atomicAdd(&gcnt[i], h) : 0;   // reserve [cur, cur+h)
    }
    __syncthreads();
    for (int i = t; i < lim; i += 256) {
        int b = bbuf[i];
        int p = atomicAdd(&cur[b], 1);
        if (p >= 0 && p < CAP) pairs[(size_t)b * CAP + p] = vbuf[i];
    }
}

// ==================== layer-1 projection (x @ W1) -> fp16 rows ====================
// block = 256 threads = 16 nodes x 16 out-channels
__global__ void proj1_k(const float* __restrict__ x, const float* __restrict__ W1,
                        const float* __restrict__ att_s, const float* __restrict__ att_d,
                        __half* __restrict__ h1f, float* __restrict__ a_src,
                        float* __restrict__ a_dst) {
    __shared__ float sW[IN_C * HID];   // 8 KB
    __shared__ float sX[16 * IN_C];    // 8 KB
    __shared__ float sH[16 * HID];
    int t = threadIdx.x;
    for (int i = t; i < IN_C * HID; i += 256) sW[i] = W1[i];
    int node0 = blockIdx.x * 16;
    for (int i = t; i < 16 * IN_C; i += 256) {
        int r = i >> 7, c = i & 127;
        int node = node0 + r;
        sX[i] = (node < N_NODES) ? x[(size_t)node * IN_C + c] : 0.0f;
    }
    __syncthreads();
    int r = t >> 4, c = t & 15;
    int node = node0 + r;
    float acc = 0.0f;
    #pragma unroll 8
    for (int k = 0; k < IN_C; ++k) acc += sX[r * IN_C + k] * sW[k * HID + c];
    sH[r * HID + c] = acc;
    if (node < N_NODES) h1f[(size_t)node * HID + c] = __float2half(acc);
    __syncthreads();
    if (c == 0 && node < N_NODES) {
        float s = 0.0f, d = 0.0f;
        #pragma unroll
        for (int k = 0; k < HID; ++k) {
            float hv = sH[r * HID + k];
            s += hv * att_s[k];
            d += hv * att_d[k];
        }
        a_src[node] = s;
        a_dst[node] = d;
    }
}

// ===== layer-1: bucket-scan aggregate (LDS fp atomics) + relu + proj2 fused =====
// one block per 128-dst half-bucket: blockIdx = bucket*2 + half
__global__ __launch_bounds__(512) void gat1b_k(
    const unsigned* __restrict__ pairs, const int* __restrict__ gcnt,
    const __half* __restrict__ h1f, const float* __restrict__ asrc1,
    const float* __restrict__ adst1, const float* __restrict__ b1,
    const float* __restrict__ W2, const float* __restrict__ as2,
    const float* __restrict__ ad2, float4* __restrict__ h2p,
    float* __restrict__ adst2) {
    __shared__ float acc[128][17];    // slot 16 = denom; stride 17 -> bank spread
    __shared__ float adt[128];
    __shared__ float sW2[HID * OUTC];
    __shared__ float sB1[HID];
    __shared__ float sAs[OUTC], sAd[OUTC];
    int t = threadIdx.x;
    int bk = blockIdx.x >> 1, hh = blockIdx.x & 1;
    for (int i = t; i < 128 * 17; i += 512) ((float*)acc)[i] = 0.0f;
    if (t < HID * OUTC) sW2[t] = W2[t];
    else if (t >= 96 && t < 96 + HID) sB1[t - 96] = b1[t - 96];
    else if (t >= 128 && t < 128 + OUTC) sAs[t - 128] = as2[t - 128];
    else if (t >= 160 && t < 160 + OUTC) sAd[t - 160] = ad2[t - 160];
    if (t >= 256 && t < 384) {
        int node = (bk << 8) + (hh << 7) + (t - 256);
        adt[t - 256] = (node < N_NODES) ? adst1[node] : 0.0f;
    }
    __syncthreads();
    int tot = gcnt[bk]; if (tot > CAP) tot = CAP;
    size_t pb = (size_t)bk * CAP;
    for (int i = t; i < tot; i += 512) {
        unsigned v = pairs[pb + i];
        int dl8 = (int)(v & 255u);
        if ((dl8 >> 7) != hh) continue;
        int dl = dl8 & 127;
        int s = (int)(v >> 8);
        float e = asrc1[s] + adt[dl];
        e = (e > 0.0f) ? e : NEG_SLOPE * e;
        float ex = __expf(e);     // no max-subtraction: |e| < ~1
        const float4* hp = (const float4*)(h1f + (size_t)s * HID);
        float4 r0 = hp[0], r1 = hp[1];
        float2 f0 = unpk_half2(r0.x), f1 = unpk_half2(r0.y);
        float2 f2 = unpk_half2(r0.z), f3 = unpk_half2(r0.w);
        float2 f4 = unpk_half2(r1.x), f5 = unpk_half2(r1.y);
        float2 f6 = unpk_half2(r1.z), f7 = unpk_half2(r1.w);
        atomicAdd(&acc[dl][0],  ex * f0.x); atomicAdd(&acc[dl][1],  ex * f0.y);
        atomicAdd(&acc[dl][2],  ex * f1.x); atomicAdd(&acc[dl][3],  ex * f1.y);
        atomicAdd(&acc[dl][4],  ex * f2.x); atomicAdd(&acc[dl][5],  ex * f2.y);
        atomicAdd(&acc[dl][6],  ex * f3.x); atomicAdd(&acc[dl][7],  ex * f3.y);
        atomicAdd(&acc[dl][8],  ex * f4.x); atomicAdd(&acc[dl][9],  ex * f4.y);
        atomicAdd(&acc[dl][10], ex * f5.x); atomicAdd(&acc[dl][11], ex * f5.y);
        atomicAdd(&acc[dl][12], ex * f6.x); atomicAdd(&acc[dl][13], ex * f6.y);
        atomicAdd(&acc[dl][14], ex * f7.x); atomicAdd(&acc[dl][15], ex * f7.y);
        atomicAdd(&acc[dl][16], ex);
    }
    __syncthreads();
    if (t < 128) {
        int node = (bk << 8) + (hh << 7) + t;
        if (node < N_NODES) {
            float inv = 1.0f / (acc[t][16] + 1e-16f);
            float g[HID];
            #pragma unroll
            for (int k = 0; k < HID; ++k)
                g[k] = fmaxf(acc[t][k] * inv + sB1[k], 0.0f);
            float h2[OUTC];
            #pragma unroll
            for (int c = 0; c < OUTC; ++c) {
                float a = 0.0f;
                #pragma unroll
                for (int k = 0; k < HID; ++k) a += g[k] * sW2[k * OUTC + c];
                h2[c] = a;
            }
            float s2 = 0.0f, d2 = 0.0f;
            #pragma unroll
            for (int c = 0; c < OUTC; ++c) { s2 += h2[c] * sAs[c]; d2 += h2[c] * sAd[c]; }
            adst2[node] = d2;
            float4 r;
            r.x = s2;
            r.y = pk_half2(h2[0], h2[1]);
            r.z = pk_half2(h2[2], h2[3]);
            r.w = pk_half2(h2[4], 0.0f);
            h2p[node] = r;
        }
    }
}

// ===== layer-2: bucket-scan aggregate + bias + log_softmax -> out =====
__global__ __launch_bounds__(512) void gat2b_k(
    const unsigned* __restrict__ pairs, const int* __restrict__ gcnt,
    const float4* __restrict__ h2p, const float* __restrict__ adst2,
    const float* __restrict__ b2, float* __restrict__ out) {
    __shared__ float acc[128][7];     // slots 0..4 = channels, 5 = denom; stride 7
    __shared__ float adt[128];
    __shared__ float sB2[OUTC];
    int t = threadIdx.x;
    int bk = blockIdx.x >> 1, hh = blockIdx.x & 1;
    for (int i = t; i < 128 * 7; i += 512) ((float*)acc)[i] = 0.0f;
    if (t < OUTC) sB2[t] = b2[t];
    if (t >= 64 && t < 192) {
        int node = (bk << 8) + (hh << 7) + (t - 64);
        adt[t - 64] = (node < N_NODES) ? adst2[node] : 0.0f;
    }
    __syncthreads();
    int tot = gcnt[bk]; if (tot > CAP) tot = CAP;
    size_t pb = (size_t)bk * CAP;
    for (int i = t; i < tot; i += 512) {
        unsigned v = pairs[pb + i];
        int dl8 = (int)(v & 255u);
        if ((dl8 >> 7) != hh) continue;
        int dl = dl8 & 127;
        int s = (int)(v >> 8);
        float4 r = h2p[s];
        float e = r.x + adt[dl];
        e = (e > 0.0f) ? e : NEG_SLOPE * e;
        float ex = __expf(e);
        float2 f01 = unpk_half2(r.y);
        float2 f23 = unpk_half2(r.z);
        float2 f4_ = unpk_half2(r.w);
        atomicAdd(&acc[dl][0], ex * f01.x); atomicAdd(&acc[dl][1], ex * f01.y);
        atomicAdd(&acc[dl][2], ex * f23.x); atomicAdd(&acc[dl][3], ex * f23.y);
        atomicAdd(&acc[dl][4], ex * f4_.x);
        atomicAdd(&acc[dl][5], ex);
    }
    __syncthreads();
    if (t < 128) {
        int node = (bk << 8) + (hh << 7) + t;
        if (node < N_NODES) {
            float inv = 1.0f / (acc[t][5] + 1e-16f);
            float val[OUTC];
            float mx = -3.4e38f;
            #pragma unroll
            for (int c = 0; c < OUTC; ++c) {
                val[c] = acc[t][c] * inv + sB2[c];
                mx = fmaxf(mx, val[c]);
            }
            float se = 0.0f;
            #pragma unroll
            for (int c = 0; c < OUTC; ++c) se += __expf(val[c] - mx);
            float lse = logf(se) + mx;
            #pragma unroll
            for (int c = 0; c < OUTC; ++c)
                out[(size_t)node * OUTC + c] = val[c] - lse;
        }
    }
}

extern "C" void kernel_launch(void* const* d_in, const int* in_sizes, int n_in,
                              void* d_out, int out_size, void* d_ws, size_t ws_size,
                              hipStream_t stream) {
    const float* x    = (const float*)d_in[0];
    const int*   ei   = (const int*)d_in[1];
    const float* W1   = (const float*)d_in[2];
    const float* as1  = (const float*)d_in[3];
    const float* ad1  = (const float*)d_in[4];
    const float* b1   = (const float*)d_in[5];
    const float* W2   = (const float*)d_in[6];
    const float* as2  = (const float*)d_in[7];
    const float* ad2  = (const float*)d_in[8];
    const float* b2   = (const float*)d_in[9];
    float* out = (float*)d_out;

    // workspace layout (bytes), total ~20.4 MB — no aliasing, pairs lives to the end:
    //  pairs:  NBKT*CAP u32 = 14,413,824 B   (16B-aligned size)
    //  h2p:    N float4     =  1,600,000 B
    //  h1f:    16N __half   =  3,200,000 B
    //  asrc1:  N float
    //  adst1:  N float
    //  adst2:  N float
    //  gcnt:   NBKT int
    char* wsb = (char*)d_ws;
    unsigned* pairs = (unsigned*)wsb;
    float4* h2p     = (float4*)(wsb + (size_t)NBKT * CAP * 4);
    __half* h1f     = (__half*)((char*)h2p + (size_t)N_NODES * 16);
    float* asrc1    = (float*)((char*)h1f + (size_t)N_NODES * HID * 2);
    float* adst1    = asrc1 + N_NODES;
    float* adst2    = adst1 + N_NODES;
    int*   gcnt     = (int*)(adst2 + N_NODES);

    const int B = 256;
    const int gB = NBKT * 2;   // 782 half-bucket blocks

    // ---- bucket partition (dst-grouped) ----
    zero_gcnt_k<<<(NBKT + B - 1) / B, B, 0, stream>>>(gcnt);
    part_k<<<P1_GRID, B, 0, stream>>>(ei, gcnt, pairs);

    // ---- layer 1 projection (fp16 feature rows) ----
    proj1_k<<<(N_NODES + 15) / 16, 256, 0, stream>>>(x, W1, as1, ad1, h1f, asrc1, adst1);
    // ---- layer 1 aggregate + relu + layer-2 projection (fused, LDS atomics) ----
    gat1b_k<<<gB, 512, 0, stream>>>(pairs, gcnt, h1f, asrc1, adst1, b1,
                                    W2, as2, ad2, h2p, adst2);
    // ---- layer 2 aggregate + log_softmax ----
    gat2b_k<<<gB, 512, 0, stream>>>(pairs, gcnt, h2p, adst2, b2, out);
}

// Round 7
// 274.319 us; speedup vs baseline: 2.4638x; 2.4638x over previous
//
#include <hip/hip_runtime.h>
#include <hip/hip_fp16.h>

#define N_NODES 100000
#define N_EDGES 3200000
#define E_TOT   (N_EDGES + N_NODES)   // 3.3M edges incl self-loops
#define IN_C 128
#define HID  16
#define OUTC 5
#define NEG_SLOPE 0.2f

#define NBKT 391          // buckets of 256 dst nodes: b = dst >> 8
#define CAP  9216         // per-bucket capacity (mean 8448, +8.5 sigma)
#define P1_TILE 8192
#define P1_GRID ((E_TOT + P1_TILE - 1) / P1_TILE)   // 403

__device__ __forceinline__ float pk_half2(float a, float b) {
    __half2 h = __halves2half2(__float2half(a), __float2half(b));
    return *(float*)&h;
}
__device__ __forceinline__ float2 unpk_half2(float v) {
    return __half22float2(*(__half2*)&v);
}

// ==================== phase 0: zero bucket totals ====================
__global__ void zero_gcnt_k(int* __restrict__ gcnt) {
    int i = blockIdx.x * blockDim.x + threadIdx.x;
    if (i < NBKT) gcnt[i] = 0;
}

// ==================== phase 1: partition edges by dst>>8 ====================
// packed entry: (src << 8) | (dst & 255)
__global__ __launch_bounds__(256) void part_k(const int* __restrict__ ei,
                                              int* __restrict__ gcnt,
                                              unsigned* __restrict__ pairs) {
    __shared__ unsigned vbuf[P1_TILE];        // 32 KB
    __shared__ unsigned short bbuf[P1_TILE];  // 16 KB
    __shared__ int hist[NBKT];
    __shared__ int cur[NBKT];
    int t = threadIdx.x;
    for (int i = t; i < NBKT; i += 256) hist[i] = 0;
    __syncthreads();
    int base = blockIdx.x * P1_TILE;
    int lim = E_TOT - base; if (lim > P1_TILE) lim = P1_TILE;
    for (int i = t; i < lim; i += 256) {
        int e = base + i;
        int s, d;
        if (e < N_EDGES) { s = ei[e]; d = ei[N_EDGES + e]; }
        else             { s = e - N_EDGES; d = s; }
        int b = d >> 8;
        vbuf[i] = ((unsigned)s << 8) | (unsigned)(d & 255);
        bbuf[i] = (unsigned short)b;
        atomicAdd(&hist[b], 1);
    }
    __syncthreads();
    for (int i = t; i < NBKT; i += 256) {
        int h = hist[i];
        cur[i] = h ? atomicAdd(&gcnt[i], h) : 0;
    }
    __syncthreads();
    for (int i = t; i < lim; i += 256) {
        int b = bbuf[i];
        int p = atomicAdd(&cur[b], 1);
        if (p >= 0 && p < CAP) pairs[(size_t)b * CAP + p] = vbuf[i];
    }
}

// ============ exclusive scan of bucket totals -> bucket csr base ============
__global__ void scan_gcnt_k(const int* __restrict__ gcnt, int* __restrict__ cbase) {
    __shared__ int s[512];
    int t = threadIdx.x;
    int v = (t < NBKT) ? gcnt[t] : 0;
    s[t] = v; __syncthreads();
    for (int off = 1; off < 512; off <<= 1) {
        int x = (t >= off) ? s[t - off] : 0;
        __syncthreads();
        s[t] += x;
        __syncthreads();
    }
    if (t < NBKT) cbase[t] = s[t] - v;
}

// ======== phase 2: per-bucket CSR build (LDS counters only) ====
__global__ __launch_bounds__(256) void build_k(const unsigned* __restrict__ pairs,
                                               const int* __restrict__ gcnt,
                                               const int* __restrict__ cbase,
                                               int* __restrict__ csr,
                                               int* __restrict__ row_start,
                                               int* __restrict__ cnt) {
    __shared__ int c[256], s[256], cur[256];
    int t = threadIdx.x;
    int b = blockIdx.x;
    c[t] = 0;
    __syncthreads();
    int tot = gcnt[b];
    if (tot > CAP) tot = CAP;
    size_t pbase = (size_t)b * CAP;
    for (int i = t; i < tot; i += 256) atomicAdd(&c[pairs[pbase + i] & 255u], 1);
    __syncthreads();
    int v0 = c[t];
    s[t] = v0; __syncthreads();
    for (int off = 1; off < 256; off <<= 1) {
        int x = (t >= off) ? s[t - off] : 0;
        __syncthreads();
        s[t] += x;
        __syncthreads();
    }
    int excl = s[t] - v0;
    int gbase = cbase[b];
    int node = (b << 8) + t;
    if (node < N_NODES) { row_start[node] = gbase + excl; cnt[node] = v0; }
    cur[t] = gbase + excl;
    __syncthreads();
    for (int i = t; i < tot; i += 256) {
        unsigned v = pairs[pbase + i];
        int pos = atomicAdd(&cur[v & 255u], 1);
        csr[pos] = (int)(v >> 8);
    }
}

// ==================== layer-1 projection (x @ W1) -> fp16 rows ====================
__global__ void proj1_k(const float* __restrict__ x, const float* __restrict__ W1,
                        const float* __restrict__ att_s, const float* __restrict__ att_d,
                        __half* __restrict__ h1f, float* __restrict__ a_src,
                        float* __restrict__ a_dst) {
    __shared__ float sW[IN_C * HID];   // 8 KB
    __shared__ float sX[16 * IN_C];    // 8 KB
    __shared__ float sH[16 * HID];
    int t = threadIdx.x;
    for (int i = t; i < IN_C * HID; i += 256) sW[i] = W1[i];
    int node0 = blockIdx.x * 16;
    for (int i = t; i < 16 * IN_C; i += 256) {
        int r = i >> 7, c = i & 127;
        int node = node0 + r;
        sX[i] = (node < N_NODES) ? x[(size_t)node * IN_C + c] : 0.0f;
    }
    __syncthreads();
    int r = t >> 4, c = t & 15;
    int node = node0 + r;
    float acc = 0.0f;
    #pragma unroll 8
    for (int k = 0; k < IN_C; ++k) acc += sX[r * IN_C + k] * sW[k * HID + c];
    sH[r * HID + c] = acc;
    if (node < N_NODES) h1f[(size_t)node * HID + c] = __float2half(acc);
    __syncthreads();
    if (c == 0 && node < N_NODES) {
        float s = 0.0f, d = 0.0f;
        #pragma unroll
        for (int k = 0; k < HID; ++k) {
            float hv = sH[r * HID + k];
            s += hv * att_s[k];
            d += hv * att_d[k];
        }
        a_src[node] = s;
        a_dst[node] = d;
    }
}

// ===== layer-1 aggregate (CSR, 16 lanes/node, reg accum) + relu + proj2 fused =====
__global__ __launch_bounds__(256) void gat1_k(
    const int* __restrict__ csr, const int* __restrict__ row_start,
    const int* __restrict__ cnt, const __half* __restrict__ h1f,
    const float* __restrict__ a_src1, const float* __restrict__ a_dst1,
    const float* __restrict__ b1, const float* __restrict__ W2,
    const float* __restrict__ as2, const float* __restrict__ ad2,
    float4* __restrict__ h2p, float* __restrict__ a_dst2) {
    __shared__ float sW2[HID * OUTC];
    __shared__ float sB1[HID];
    __shared__ float sAs[OUTC], sAd[OUTC];
    int t = threadIdx.x;
    if (t < HID * OUTC) sW2[t] = W2[t];
    if (t < HID) sB1[t] = b1[t];
    if (t < OUTC) { sAs[t] = as2[t]; sAd[t] = ad2[t]; }
    __syncthreads();

    int node = (blockIdx.x * 256 + t) >> 4;
    int lane = t & 15;
    int start = row_start[node];
    int len   = cnt[node];
    float ad  = a_dst1[node];

    float acc[HID];
    #pragma unroll
    for (int c = 0; c < HID; ++c) acc[c] = 0.0f;
    float accd = 0.0f;
    for (int it = lane; it < len; it += 16) {
        int s = csr[start + it];
        float v = a_src1[s] + ad;
        v = (v > 0.0f) ? v : NEG_SLOPE * v;
        float ex = __expf(v);     // no max-subtraction: |v| < ~1
        accd += ex;
        const float4* hp = (const float4*)(h1f + (size_t)s * HID);  // 32B row
        float4 r0 = hp[0], r1 = hp[1];
        float2 f0 = unpk_half2(r0.x), f1 = unpk_half2(r0.y);
        float2 f2 = unpk_half2(r0.z), f3 = unpk_half2(r0.w);
        float2 f4 = unpk_half2(r1.x), f5 = unpk_half2(r1.y);
        float2 f6 = unpk_half2(r1.z), f7 = unpk_half2(r1.w);
        acc[0]  += ex * f0.x; acc[1]  += ex * f0.y;
        acc[2]  += ex * f1.x; acc[3]  += ex * f1.y;
        acc[4]  += ex * f2.x; acc[5]  += ex * f2.y;
        acc[6]  += ex * f3.x; acc[7]  += ex * f3.y;
        acc[8]  += ex * f4.x; acc[9]  += ex * f4.y;
        acc[10] += ex * f5.x; acc[11] += ex * f5.y;
        acc[12] += ex * f6.x; acc[13] += ex * f6.y;
        acc[14] += ex * f7.x; acc[15] += ex * f7.y;
    }
    #pragma unroll
    for (int off = 8; off; off >>= 1) {
        accd += __shfl_xor(accd, off);
        #pragma unroll
        for (int c = 0; c < HID; ++c) acc[c] += __shfl_xor(acc[c], off);
    }
    if (lane == 0) {
        float inv = 1.0f / (accd + 1e-16f);
        float g[HID];
        #pragma unroll
        for (int k = 0; k < HID; ++k) g[k] = fmaxf(acc[k] * inv + sB1[k], 0.0f);
        float h2[OUTC];
        #pragma unroll
        for (int c = 0; c < OUTC; ++c) {
            float a = 0.0f;
            #pragma unroll
            for (int k = 0; k < HID; ++k) a += g[k] * sW2[k * OUTC + c];
            h2[c] = a;
        }
        float s2 = 0.0f, d2 = 0.0f;
        #pragma unroll
        for (int c = 0; c < OUTC; ++c) { s2 += h2[c] * sAs[c]; d2 += h2[c] * sAd[c]; }
        a_dst2[node] = d2;
        float4 r;
        r.x = s2;
        r.y = pk_half2(h2[0], h2[1]);
        r.z = pk_half2(h2[2], h2[3]);
        r.w = pk_half2(h2[4], 0.0f);
        h2p[node] = r;
    }
}

// ===== layer-2 aggregate + bias + log_softmax -> out =====
__global__ __launch_bounds__(256) void gat2_k(
    const int* __restrict__ csr, const int* __restrict__ row_start,
    const int* __restrict__ cnt, const float4* __restrict__ h2p,
    const float* __restrict__ a_dst2, const float* __restrict__ b2,
    float* __restrict__ out) {
    __shared__ float sB2[OUTC];
    int t = threadIdx.x;
    if (t < OUTC) sB2[t] = b2[t];
    __syncthreads();

    int node = (blockIdx.x * 256 + t) >> 4;
    int lane = t & 15;
    int start = row_start[node];
    int len   = cnt[node];
    float ad  = a_dst2[node];

    float acc[OUTC];
    #pragma unroll
    for (int c = 0; c < OUTC; ++c) acc[c] = 0.0f;
    float accd = 0.0f;
    for (int it = lane; it < len; it += 16) {
        int s = csr[start + it];
        float4 r = h2p[s];   // [asrc2 | h0h1 | h2h3 | h4--] 16B
        float v = r.x + ad;
        v = (v > 0.0f) ? v : NEG_SLOPE * v;
        float ex = __expf(v);
        accd += ex;
        float2 f01 = unpk_half2(r.y);
        float2 f23 = unpk_half2(r.z);
        float2 f4_ = unpk_half2(r.w);
        acc[0] += ex * f01.x; acc[1] += ex * f01.y;
        acc[2] += ex * f23.x; acc[3] += ex * f23.y;
        acc[4] += ex * f4_.x;
    }
    #pragma unroll
    for (int off = 8; off; off >>= 1) {
        accd += __shfl_xor(accd, off);
        #pragma unroll
        for (int c = 0; c < OUTC; ++c) acc[c] += __shfl_xor(acc[c], off);
    }
    if (lane == 0) {
        float inv = 1.0f / (accd + 1e-16f);
        float val[OUTC];
        float mx = -3.4e38f;
        #pragma unroll
        for (int c = 0; c < OUTC; ++c) {
            val[c] = acc[c] * inv + sB2[c];
            mx = fmaxf(mx, val[c]);
        }
        float se = 0.0f;
        #pragma unroll
        for (int c = 0; c < OUTC; ++c) se += __expf(val[c] - mx);
        float lse = logf(se) + mx;
        #pragma unroll
        for (int c = 0; c < OUTC; ++c)
            out[(size_t)node * OUTC + c] = val[c] - lse;
    }
}

extern "C" void kernel_launch(void* const* d_in, const int* in_sizes, int n_in,
                              void* d_out, int out_size, void* d_ws, size_t ws_size,
                              hipStream_t stream) {
    const float* x    = (const float*)d_in[0];
    const int*   ei   = (const int*)d_in[1];
    const float* W1   = (const float*)d_in[2];
    const float* as1  = (const float*)d_in[3];
    const float* ad1  = (const float*)d_in[4];
    const float* b1   = (const float*)d_in[5];
    const float* W2   = (const float*)d_in[6];
    const float* as2  = (const float*)d_in[7];
    const float* ad2  = (const float*)d_in[8];
    const float* b2   = (const float*)d_in[9];
    float* out = (float*)d_out;

    // workspace (bytes):
    //  region A: pairs NBKT*CAP*4 = 14,413,824 B -- dead after build_k, then:
    //     h1f   = A + 0           (16N halves, 3.2 MB, 32B-aligned rows)
    //     h2p   = A + 3,200,000   (N float4, 1.6 MB, 16B-aligned)
    //     asrc1 = A + 4,800,000   (N floats)
    //     adst1 = + N floats
    //     adst2 = + N floats      (total 6.0 MB <= 14.4 MB ok)
    //  csr:       E_TOT ints
    //  cnt:       N ints
    //  row_start: N ints
    //  gcnt:      NBKT ints
    //  cbase:     512 ints
    char* wsb = (char*)d_ws;
    unsigned* pairs = (unsigned*)wsb;
    __half* h1f     = (__half*)wsb;
    float4* h2p     = (float4*)(wsb + 3200000);
    float*  asrc1   = (float*)(wsb + 4800000);
    float*  adst1   = asrc1 + N_NODES;
    float*  adst2   = adst1 + N_NODES;
    int* csr       = (int*)(wsb + (size_t)NBKT * CAP * 4);
    int* cnt       = csr + E_TOT;
    int* row_start = cnt + N_NODES;
    int* gcnt      = row_start + N_NODES;
    int* cbase     = gcnt + NBKT;

    const int B = 256;
    const int gW = (N_NODES * 16) / B;   // 6250, exact

    // ---- CSR build (dst-sorted), LDS-privatized ----
    zero_gcnt_k<<<(NBKT + B - 1) / B, B, 0, stream>>>(gcnt);
    part_k<<<P1_GRID, B, 0, stream>>>(ei, gcnt, pairs);
    scan_gcnt_k<<<1, 512, 0, stream>>>(gcnt, cbase);
    build_k<<<NBKT, B, 0, stream>>>(pairs, gcnt, cbase, csr, row_start, cnt);

    // ---- layer 1 projection (fp16 rows; pairs region now dead) ----
    proj1_k<<<(N_NODES + 15) / 16, 256, 0, stream>>>(x, W1, as1, ad1, h1f, asrc1, adst1);
    // ---- layer 1 aggregate + relu + layer-2 projection (fused) ----
    gat1_k<<<gW, B, 0, stream>>>(csr, row_start, cnt, h1f, asrc1, adst1, b1,
                                 W2, as2, ad2, h2p, adst2);
    // ---- layer 2 aggregate + log_softmax ----
    gat2_k<<<gW, B, 0, stream>>>(csr, row_start, cnt, h2p, adst2, b2, out);
}

// Round 8
// 270.332 us; speedup vs baseline: 2.5001x; 1.0147x over previous
//
#include <hip/hip_runtime.h>
#include <hip/hip_fp16.h>

#define N_NODES 100000
#define N_EDGES 3200000
#define E_TOT   (N_EDGES + N_NODES)   // 3.3M edges incl self-loops
#define IN_C 128
#define HID  16
#define OUTC 5
#define NEG_SLOPE 0.2f

#define NBKT 782          // buckets of 128 dst nodes: b = dst >> 7
#define CAP  4608         // per-bucket capacity (mean 4224, +6 sigma)
#define P_TILE 8192
#define P_GRID ((E_TOT + P_TILE - 1) / P_TILE)   // 403

__device__ __forceinline__ float pk_half2(float a, float b) {
    __half2 h = __halves2half2(__float2half(a), __float2half(b));
    return *(float*)&h;
}
__device__ __forceinline__ float2 unpk_half2(float v) {
    return __half22float2(*(__half2*)&v);
}

// ==================== phase 0: zero bucket totals ====================
__global__ void zero_gcnt_k(int* __restrict__ gcnt) {
    int i = blockIdx.x * blockDim.x + threadIdx.x;
    if (i < NBKT) gcnt[i] = 0;
}

// ==================== phase 1: partition edges by dst>>7 ====================
// slim: no LDS staging; pass2 re-reads the (L2-hot) edge window.
// packed entry: (src << 7) | (dst & 127)   (src < 2^17 -> 24 bits)
__global__ __launch_bounds__(512) void part_k(const int* __restrict__ ei,
                                              int* __restrict__ gcnt,
                                              unsigned* __restrict__ pairs) {
    __shared__ int hist[NBKT];
    __shared__ int cur[NBKT];
    int t = threadIdx.x;
    for (int i = t; i < NBKT; i += 512) hist[i] = 0;
    __syncthreads();
    int base = blockIdx.x * P_TILE;
    int lim = E_TOT - base; if (lim > P_TILE) lim = P_TILE;
    // pass 1: histogram (dst row only)
    for (int i = t; i < lim; i += 512) {
        int e = base + i;
        int d = (e < N_EDGES) ? ei[N_EDGES + e] : (e - N_EDGES);
        atomicAdd(&hist[d >> 7], 1);
    }
    __syncthreads();
    for (int i = t; i < NBKT; i += 512) {
        int h = hist[i];
        cur[i] = h ? atomicAdd(&gcnt[i], h) : 0;   // reserve [cur, cur+h)
    }
    __syncthreads();
    // pass 2: scatter (src + dst rows; dst re-read hits L2)
    for (int i = t; i < lim; i += 512) {
        int e = base + i;
        int s, d;
        if (e < N_EDGES) { s = ei[e]; d = ei[N_EDGES + e]; }
        else             { s = e - N_EDGES; d = s; }
        int b = d >> 7;
        int p = atomicAdd(&cur[b], 1);
        if (p >= 0 && p < CAP) pairs[(size_t)b * CAP + p] = ((unsigned)s << 7) | (unsigned)(d & 127);
    }
}

// ============ exclusive scan of bucket totals -> bucket csr base ============
__global__ void scan_gcnt_k(const int* __restrict__ gcnt, int* __restrict__ cbase) {
    __shared__ int s[1024];
    int t = threadIdx.x;
    int v = (t < NBKT) ? gcnt[t] : 0;
    s[t] = v; __syncthreads();
    for (int off = 1; off < 1024; off <<= 1) {
        int x = (t >= off) ? s[t - off] : 0;
        __syncthreads();
        s[t] += x;
        __syncthreads();
    }
    if (t < NBKT) cbase[t] = s[t] - v;
}

// ======== phase 2: per-bucket CSR build (128 nodes/block, LDS counters) ====
__global__ __launch_bounds__(256) void build_k(const unsigned* __restrict__ pairs,
                                               const int* __restrict__ gcnt,
                                               const int* __restrict__ cbase,
                                               int* __restrict__ csr,
                                               int* __restrict__ row_start,
                                               int* __restrict__ cnt) {
    __shared__ int c[128], s[128], cur[128];
    int t = threadIdx.x;
    int b = blockIdx.x;
    if (t < 128) c[t] = 0;
    __syncthreads();
    int tot = gcnt[b];
    if (tot > CAP) tot = CAP;
    size_t pbase = (size_t)b * CAP;
    for (int i = t; i < tot; i += 256) atomicAdd(&c[pairs[pbase + i] & 127u], 1);
    __syncthreads();
    if (t < 128) { s[t] = c[t]; }
    __syncthreads();
    for (int off = 1; off < 128; off <<= 1) {
        int x = (t < 128 && t >= off) ? s[t - off] : 0;
        __syncthreads();
        if (t < 128) s[t] += x;
        __syncthreads();
    }
    int gbase = cbase[b];
    if (t < 128) {
        int excl = s[t] - c[t];
        int node = (b << 7) + t;
        if (node < N_NODES) { row_start[node] = gbase + excl; cnt[node] = c[t]; }
        cur[t] = gbase + excl;
    }
    __syncthreads();
    for (int i = t; i < tot; i += 256) {
        unsigned v = pairs[pbase + i];
        int pos = atomicAdd(&cur[v & 127u], 1);
        csr[pos] = (int)(v >> 7);
    }
}

// ==================== layer-1 projection (x @ W1) -> fp16 rows ====================
__global__ void proj1_k(const float* __restrict__ x, const float* __restrict__ W1,
                        const float* __restrict__ att_s, const float* __restrict__ att_d,
                        __half* __restrict__ h1f, float* __restrict__ a_src,
                        float* __restrict__ a_dst) {
    __shared__ float sW[IN_C * HID];   // 8 KB
    __shared__ float sX[16 * IN_C];    // 8 KB
    __shared__ float sH[16 * HID];
    int t = threadIdx.x;
    const float4* W4 = (const float4*)W1;
    for (int i = t; i < IN_C * HID / 4; i += 256) ((float4*)sW)[i] = W4[i];
    int node0 = blockIdx.x * 16;
    const float4* x4 = (const float4*)x;
    for (int i = t; i < 16 * IN_C / 4; i += 256) {
        int r = i >> 5, c4 = i & 31;      // 32 float4 per row
        int node = node0 + r;
        float4 v = make_float4(0.f, 0.f, 0.f, 0.f);
        if (node < N_NODES) v = x4[(size_t)node * 32 + c4];
        *((float4*)&sX[r * IN_C + c4 * 4]) = v;
    }
    __syncthreads();
    int r = t >> 4, c = t & 15;
    int node = node0 + r;
    float acc = 0.0f;
    #pragma unroll 8
    for (int k = 0; k < IN_C; ++k) acc += sX[r * IN_C + k] * sW[k * HID + c];
    sH[r * HID + c] = acc;
    if (node < N_NODES) h1f[(size_t)node * HID + c] = __float2half(acc);
    __syncthreads();
    if (c == 0 && node < N_NODES) {
        float s = 0.0f, d = 0.0f;
        #pragma unroll
        for (int k = 0; k < HID; ++k) {
            float hv = sH[r * HID + k];
            s += hv * att_s[k];
            d += hv * att_d[k];
        }
        a_src[node] = s;
        a_dst[node] = d;
    }
}

// ===== layer-1 aggregate (CSR, 4 lanes/node) + relu + proj2 fused =====
__global__ __launch_bounds__(256) void gat1_k(
    const int* __restrict__ csr, const int* __restrict__ row_start,
    const int* __restrict__ cnt, const __half* __restrict__ h1f,
    const float* __restrict__ a_src1, const float* __restrict__ a_dst1,
    const float* __restrict__ b1, const float* __restrict__ W2,
    const float* __restrict__ as2, const float* __restrict__ ad2,
    float4* __restrict__ h2p, float* __restrict__ a_dst2) {
    __shared__ float sW2[HID * OUTC];
    __shared__ float sB1[HID];
    __shared__ float sAs[OUTC], sAd[OUTC];
    int t = threadIdx.x;
    if (t < HID * OUTC) sW2[t] = W2[t];
    if (t < HID) sB1[t] = b1[t];
    if (t < OUTC) { sAs[t] = as2[t]; sAd[t] = ad2[t]; }
    __syncthreads();

    int node = (blockIdx.x * 256 + t) >> 2;
    if (node >= N_NODES) return;
    int lane = t & 3;
    int start = row_start[node];
    int len   = cnt[node];
    float ad  = a_dst1[node];

    float acc[HID];
    #pragma unroll
    for (int c = 0; c < HID; ++c) acc[c] = 0.0f;
    float accd = 0.0f;
    for (int it = lane; it < len; it += 4) {
        int s = csr[start + it];
        float v = a_src1[s] + ad;
        v = (v > 0.0f) ? v : NEG_SLOPE * v;
        float ex = __expf(v);     // no max-subtraction: |v| < ~1
        accd += ex;
        const float4* hp = (const float4*)(h1f + (size_t)s * HID);  // 32B row
        float4 r0 = hp[0], r1 = hp[1];
        float2 f0 = unpk_half2(r0.x), f1 = unpk_half2(r0.y);
        float2 f2 = unpk_half2(r0.z), f3 = unpk_half2(r0.w);
        float2 f4 = unpk_half2(r1.x), f5 = unpk_half2(r1.y);
        float2 f6 = unpk_half2(r1.z), f7 = unpk_half2(r1.w);
        acc[0]  += ex * f0.x; acc[1]  += ex * f0.y;
        acc[2]  += ex * f1.x; acc[3]  += ex * f1.y;
        acc[4]  += ex * f2.x; acc[5]  += ex * f2.y;
        acc[6]  += ex * f3.x; acc[7]  += ex * f3.y;
        acc[8]  += ex * f4.x; acc[9]  += ex * f4.y;
        acc[10] += ex * f5.x; acc[11] += ex * f5.y;
        acc[12] += ex * f6.x; acc[13] += ex * f6.y;
        acc[14] += ex * f7.x; acc[15] += ex * f7.y;
    }
    #pragma unroll
    for (int off = 2; off; off >>= 1) {
        accd += __shfl_xor(accd, off);
        #pragma unroll
        for (int c = 0; c < HID; ++c) acc[c] += __shfl_xor(acc[c], off);
    }
    if (lane == 0) {
        float inv = 1.0f / (accd + 1e-16f);
        float g[HID];
        #pragma unroll
        for (int k = 0; k < HID; ++k) g[k] = fmaxf(acc[k] * inv + sB1[k], 0.0f);
        float h2[OUTC];
        #pragma unroll
        for (int c = 0; c < OUTC; ++c) {
            float a = 0.0f;
            #pragma unroll
            for (int k = 0; k < HID; ++k) a += g[k] * sW2[k * OUTC + c];
            h2[c] = a;
        }
        float s2 = 0.0f, d2 = 0.0f;
        #pragma unroll
        for (int c = 0; c < OUTC; ++c) { s2 += h2[c] * sAs[c]; d2 += h2[c] * sAd[c]; }
        a_dst2[node] = d2;
        float4 r;
        r.x = s2;
        r.y = pk_half2(h2[0], h2[1]);
        r.z = pk_half2(h2[2], h2[3]);
        r.w = pk_half2(h2[4], 0.0f);
        h2p[node] = r;
    }
}

// ===== layer-2 aggregate (4 lanes/node) + bias + log_softmax -> out =====
__global__ __launch_bounds__(256) void gat2_k(
    const int* __restrict__ csr, const int* __restrict__ row_start,
    const int* __restrict__ cnt, const float4* __restrict__ h2p,
    const float* __restrict__ a_dst2, const float* __restrict__ b2,
    float* __restrict__ out) {
    __shared__ float sB2[OUTC];
    int t = threadIdx.x;
    if (t < OUTC) sB2[t] = b2[t];
    __syncthreads();

    int node = (blockIdx.x * 256 + t) >> 2;
    if (node >= N_NODES) return;
    int lane = t & 3;
    int start = row_start[node];
    int len   = cnt[node];
    float ad  = a_dst2[node];

    float acc[OUTC];
    #pragma unroll
    for (int c = 0; c < OUTC; ++c) acc[c] = 0.0f;
    float accd = 0.0f;
    for (int it = lane; it < len; it += 4) {
        int s = csr[start + it];
        float4 r = h2p[s];   // [asrc2 | h0h1 | h2h3 | h4--] 16B
        float v = r.x + ad;
        v = (v > 0.0f) ? v : NEG_SLOPE * v;
        float ex = __expf(v);
        accd += ex;
        float2 f01 = unpk_half2(r.y);
        float2 f23 = unpk_half2(r.z);
        float2 f4_ = unpk_half2(r.w);
        acc[0] += ex * f01.x; acc[1] += ex * f01.y;
        acc[2] += ex * f23.x; acc[3] += ex * f23.y;
        acc[4] += ex * f4_.x;
    }
    #pragma unroll
    for (int off = 2; off; off >>= 1) {
        accd += __shfl_xor(accd, off);
        #pragma unroll
        for (int c = 0; c < OUTC; ++c) acc[c] += __shfl_xor(acc[c], off);
    }
    if (lane == 0) {
        float inv = 1.0f / (accd + 1e-16f);
        float val[OUTC];
        float mx = -3.4e38f;
        #pragma unroll
        for (int c = 0; c < OUTC; ++c) {
            val[c] = acc[c] * inv + sB2[c];
            mx = fmaxf(mx, val[c]);
        }
        float se = 0.0f;
        #pragma unroll
        for (int c = 0; c < OUTC; ++c) se += __expf(val[c] - mx);
        float lse = logf(se) + mx;
        #pragma unroll
        for (int c = 0; c < OUTC; ++c)
            out[(size_t)node * OUTC + c] = val[c] - lse;
    }
}

extern "C" void kernel_launch(void* const* d_in, const int* in_sizes, int n_in,
                              void* d_out, int out_size, void* d_ws, size_t ws_size,
                              hipStream_t stream) {
    const float* x    = (const float*)d_in[0];
    const int*   ei   = (const int*)d_in[1];
    const float* W1   = (const float*)d_in[2];
    const float* as1  = (const float*)d_in[3];
    const float* ad1  = (const float*)d_in[4];
    const float* b1   = (const float*)d_in[5];
    const float* W2   = (const float*)d_in[6];
    const float* as2  = (const float*)d_in[7];
    const float* ad2  = (const float*)d_in[8];
    const float* b2   = (const float*)d_in[9];
    float* out = (float*)d_out;

    // workspace (bytes), ~28.4 MB:
    //  region A: pairs NBKT*CAP*4 = 14,413,824 B -- dead after build_k, then:
    //     h1f   = A + 0           (16N halves, 3.2 MB)
    //     h2p   = A + 3,200,000   (N float4, 1.6 MB)
    //     asrc1 = A + 4,800,000   (N floats)
    //     adst1 = + N floats
    //     adst2 = + N floats      (total 6.0 MB <= 14.4 MB ok)
    //  csr:       E_TOT ints
    //  cnt:       N ints
    //  row_start: N ints
    //  gcnt:      NBKT ints
    //  cbase:     1024 ints
    char* wsb = (char*)d_ws;
    unsigned* pairs = (unsigned*)wsb;
    __half* h1f     = (__half*)wsb;
    float4* h2p     = (float4*)(wsb + 3200000);
    float*  asrc1   = (float*)(wsb + 4800000);
    float*  adst1   = asrc1 + N_NODES;
    float*  adst2   = adst1 + N_NODES;
    int* csr       = (int*)(wsb + (size_t)NBKT * CAP * 4);
    int* cnt       = csr + E_TOT;
    int* row_start = cnt + N_NODES;
    int* gcnt      = row_start + N_NODES;
    int* cbase     = gcnt + NBKT;

    const int B = 256;
    const int gW = (N_NODES * 4 + B - 1) / B;   // 1563

    // ---- CSR build (dst-sorted), LDS-privatized ----
    zero_gcnt_k<<<(NBKT + B - 1) / B, B, 0, stream>>>(gcnt);
    part_k<<<P_GRID, 512, 0, stream>>>(ei, gcnt, pairs);
    scan_gcnt_k<<<1, 1024, 0, stream>>>(gcnt, cbase);
    build_k<<<NBKT, B, 0, stream>>>(pairs, gcnt, cbase, csr, row_start, cnt);

    // ---- layer 1 projection (fp16 rows; pairs region dead after build) ----
    proj1_k<<<(N_NODES + 15) / 16, 256, 0, stream>>>(x, W1, as1, ad1, h1f, asrc1, adst1);
    // ---- layer 1 aggregate + relu + layer-2 projection (fused) ----
    gat1_k<<<gW, B, 0, stream>>>(csr, row_start, cnt, h1f, asrc1, adst1, b1,
                                 W2, as2, ad2, h2p, adst2);
    // ---- layer 2 aggregate + log_softmax ----
    gat2_k<<<gW, B, 0, stream>>>(csr, row_start, cnt, h2p, adst2, b2, out);
}